// Round 3
// baseline (14.083 us; speedup 1.0000x reference)
//
#include <hip/hip_runtime.h>
#include <hip/hip_bf16.h>

// CentersDistance: logits[c][q] = -||c-q||^2 = 2*dot(c,q) - ||c||^2 - ||q||^2
// inputs: [4096][128] f32, centers: [256][128] f32, out: [256][4096] f32
//
// v3: latency-oriented rewrite.
//  - 16c x 16q per wave -> 4096 waves -> 4 waves/SIMD (was 1): TLP hides L2 lat.
//  - Norms fused into fragment loads (square the floats we already load,
//    shfl_xor reduce) -> no separate norm pass, no LDS, no barriers.
//  - Cross-term: single mfma_f32_16x16x32_bf16 chain, K = 4 steps.

typedef __attribute__((ext_vector_type(8))) short short8;  // 8 bf16
typedef __attribute__((ext_vector_type(4))) float f32x4;

constexpr int QN = 4096;
constexpr int CN = 256;
constexpr int DK = 128;

static __device__ inline short f2bf(float x) {
    __hip_bfloat16 h = __float2bfloat16(x);   // RNE; compiler emits cvt_pk pairs
    return __builtin_bit_cast(short, h);
}

__global__ __launch_bounds__(256) void centers_dist_v3(
    const float* __restrict__ inputs,
    const float* __restrict__ centers,
    float* __restrict__ out)
{
    const int tid  = threadIdx.x;
    const int lane = tid & 63;
    const int wid  = tid >> 6;             // 0..3 : q sub-tile within block
    const int c0   = blockIdx.x * 16;      // 16 c-tiles
    const int q0   = blockIdx.y * 64 + wid * 16;  // 64 q-tiles of 64 (16/wave)
    const int lr   = lane & 15;            // fragment row
    const int lg   = lane >> 4;            // k-group 0..3
    const int lk   = lg * 8;               // 8 consecutive k per lane

    const float* cp = &centers[(c0 + lr) * DK + lk];
    const float* qp = &inputs [(q0 + lr) * DK + lk];

    f32x4 acc = {};
    float csum = 0.f, qsum = 0.f;

    #pragma unroll
    for (int ks = 0; ks < 4; ++ks) {
        float4 a0 = *reinterpret_cast<const float4*>(cp + ks * 32);
        float4 a1 = *reinterpret_cast<const float4*>(cp + ks * 32 + 4);
        float4 b0 = *reinterpret_cast<const float4*>(qp + ks * 32);
        float4 b1 = *reinterpret_cast<const float4*>(qp + ks * 32 + 4);

        // fp32 sq-sums of exactly the values feeding the MFMA (pre-rounding)
        csum += a0.x*a0.x + a0.y*a0.y + a0.z*a0.z + a0.w*a0.w
              + a1.x*a1.x + a1.y*a1.y + a1.z*a1.z + a1.w*a1.w;
        qsum += b0.x*b0.x + b0.y*b0.y + b0.z*b0.z + b0.w*b0.w
              + b1.x*b1.x + b1.y*b1.y + b1.z*b1.z + b1.w*b1.w;

        short8 af = short8{f2bf(a0.x), f2bf(a0.y), f2bf(a0.z), f2bf(a0.w),
                           f2bf(a1.x), f2bf(a1.y), f2bf(a1.z), f2bf(a1.w)};
        short8 bf = short8{f2bf(b0.x), f2bf(b0.y), f2bf(b0.z), f2bf(b0.w),
                           f2bf(b1.x), f2bf(b1.y), f2bf(b1.z), f2bf(b1.w)};
        acc = __builtin_amdgcn_mfma_f32_16x16x32_bf16(af, bf, acc, 0, 0, 0);
    }

    // Each lane holds the sq-sum of its 32 k-values for row lr; reduce the
    // 4 k-groups (lanes lr, lr+16, lr+32, lr+48) -> full row norms everywhere.
    csum += __shfl_xor(csum, 16);
    csum += __shfl_xor(csum, 32);
    qsum += __shfl_xor(qsum, 16);
    qsum += __shfl_xor(qsum, 32);
    // Now lane r (0..15 in each group) holds ||centers[c0+r]||^2 in csum and
    // this lane's own ||inputs[q0+lr]||^2 in qsum.

    // D-frag mapping (verified m89/m91): col = lane&15 (q), row = lg*4+j (c).
    #pragma unroll
    for (int j = 0; j < 4; ++j) {
        int cr = lg * 4 + j;
        float cn = __shfl(csum, cr);           // row-cr center norm
        out[(c0 + cr) * QN + (q0 + lr)] = fmaf(2.f, acc[j], -(cn + qsum));
    }
}

extern "C" void kernel_launch(void* const* d_in, const int* in_sizes, int n_in,
                              void* d_out, int out_size, void* d_ws, size_t ws_size,
                              hipStream_t stream) {
    const float* inputs  = (const float*)d_in[0];   // [4096][128]
    const float* centers = (const float*)d_in[1];   // [ 256][128]
    float* out = (float*)d_out;                     // [ 256][4096]

    dim3 grid(CN / 16, QN / 64);   // 16 x 64 = 1024 blocks, 4 waves each
    centers_dist_v3<<<grid, dim3(256), 0, stream>>>(inputs, centers, out);
}

// Round 4
// 11.392 us; speedup vs baseline: 1.2363x; 1.2363x over previous
//
#include <hip/hip_runtime.h>
#include <hip/hip_bf16.h>

// CentersDistance: logits[c][q] = -||c-q||^2 = 2*dot(c,q) - ||c||^2 - ||q||^2
// inputs: [4096][128] f32, centers: [256][128] f32, out: [256][4096] f32
//
// v4 = v2's reuse structure (64x64 tile/block, 4 waves of 32x32, 256 blocks
// = best traffic: 16 MB L2) + v3's norm fusion (norms computed from the very
// floats loaded for the MFMA fragments, shfl_xor-reduced in-register).
// No LDS, no barriers, single pass over the data.

typedef __attribute__((ext_vector_type(8))) short short8;  // 8 bf16
typedef __attribute__((ext_vector_type(4))) float f32x4;

constexpr int QN = 4096;
constexpr int CN = 256;
constexpr int DK = 128;

static __device__ inline short f2bf(float x) {
    __hip_bfloat16 h = __float2bfloat16(x);   // RNE; pairs fold to v_cvt_pk
    return __builtin_bit_cast(short, h);
}

__global__ __launch_bounds__(256) void centers_dist_v4(
    const float* __restrict__ inputs,
    const float* __restrict__ centers,
    float* __restrict__ out)
{
    const int tid  = threadIdx.x;
    const int lane = tid & 63;
    const int wid  = tid >> 6;        // 0..3
    const int wr   = wid >> 1;        // c-half of the 64x64 tile
    const int wc   = wid & 1;         // q-half
    const int c0   = blockIdx.x * 64;
    const int q0   = blockIdx.y * 64;
    const int lr   = lane & 15;       // fragment row
    const int lg   = lane >> 4;       // k-group 0..3
    const int lk   = lg * 8;          // 8 consecutive k per lane

    const float* cp0 = &centers[(c0 + wr * 32 +  0 + lr) * DK + lk];
    const float* cp1 = &centers[(c0 + wr * 32 + 16 + lr) * DK + lk];
    const float* qp0 = &inputs [(q0 + wc * 32 +  0 + lr) * DK + lk];
    const float* qp1 = &inputs [(q0 + wc * 32 + 16 + lr) * DK + lk];

    f32x4 acc[2][2] = {};
    float csum[2] = {0.f, 0.f};       // sq-sum partials, rows (fm*16+lr)
    float qsum[2] = {0.f, 0.f};

    #pragma unroll
    for (int ks = 0; ks < 4; ++ks) {
        const float* cps[2] = {cp0 + ks * 32, cp1 + ks * 32};
        const float* qps[2] = {qp0 + ks * 32, qp1 + ks * 32};
        short8 af[2], bfr[2];
        #pragma unroll
        for (int f = 0; f < 2; ++f) {
            float4 v0 = *reinterpret_cast<const float4*>(cps[f]);
            float4 v1 = *reinterpret_cast<const float4*>(cps[f] + 4);
            csum[f] += v0.x*v0.x + v0.y*v0.y + v0.z*v0.z + v0.w*v0.w
                     + v1.x*v1.x + v1.y*v1.y + v1.z*v1.z + v1.w*v1.w;
            af[f] = short8{f2bf(v0.x), f2bf(v0.y), f2bf(v0.z), f2bf(v0.w),
                           f2bf(v1.x), f2bf(v1.y), f2bf(v1.z), f2bf(v1.w)};
        }
        #pragma unroll
        for (int f = 0; f < 2; ++f) {
            float4 v0 = *reinterpret_cast<const float4*>(qps[f]);
            float4 v1 = *reinterpret_cast<const float4*>(qps[f] + 4);
            qsum[f] += v0.x*v0.x + v0.y*v0.y + v0.z*v0.z + v0.w*v0.w
                     + v1.x*v1.x + v1.y*v1.y + v1.z*v1.z + v1.w*v1.w;
            bfr[f] = short8{f2bf(v0.x), f2bf(v0.y), f2bf(v0.z), f2bf(v0.w),
                            f2bf(v1.x), f2bf(v1.y), f2bf(v1.z), f2bf(v1.w)};
        }
        #pragma unroll
        for (int fm = 0; fm < 2; ++fm)
            #pragma unroll
            for (int fn = 0; fn < 2; ++fn)
                acc[fm][fn] = __builtin_amdgcn_mfma_f32_16x16x32_bf16(
                    af[fm], bfr[fn], acc[fm][fn], 0, 0, 0);
    }

    // Each lane covered k in {ks*32+lg*8 .. +7}; xor over 16,32 sums the 4
    // lg-groups -> every lane holds the FULL row norm for its lr.
    #pragma unroll
    for (int f = 0; f < 2; ++f) {
        csum[f] += __shfl_xor(csum[f], 16);
        csum[f] += __shfl_xor(csum[f], 32);
        qsum[f] += __shfl_xor(qsum[f], 16);
        qsum[f] += __shfl_xor(qsum[f], 32);
    }

    // D-frag mapping (verified m89/m91): col = lane&15 (q), row = lg*4+j (c).
    #pragma unroll
    for (int fm = 0; fm < 2; ++fm) {
        #pragma unroll
        for (int fn = 0; fn < 2; ++fn) {
            int q_loc = wc * 32 + fn * 16 + lr;
            #pragma unroll
            for (int j = 0; j < 4; ++j) {
                int r = lg * 4 + j;                      // row within 16-frag
                float cn = __shfl(csum[fm], r);          // lane r holds row r
                int c_loc = wr * 32 + fm * 16 + r;
                out[(c0 + c_loc) * QN + (q0 + q_loc)] =
                    fmaf(2.f, acc[fm][fn][j], -(cn + qsum[fn]));
            }
        }
    }
}

extern "C" void kernel_launch(void* const* d_in, const int* in_sizes, int n_in,
                              void* d_out, int out_size, void* d_ws, size_t ws_size,
                              hipStream_t stream) {
    const float* inputs  = (const float*)d_in[0];   // [4096][128]
    const float* centers = (const float*)d_in[1];   // [ 256][128]
    float* out = (float*)d_out;                     // [ 256][4096]

    dim3 grid(CN / 64, QN / 64);   // 4 x 64 = 256 blocks, 4 waves each
    centers_dist_v4<<<grid, dim3(256), 0, stream>>>(inputs, centers, out);
}